// Round 11
// baseline (56.842 us; speedup 1.0000x reference)
//
#include <hip/hip_runtime.h>
#include <math.h>

#define N_SURF 40000
#define N_LIG  1024
#define HID    512
#define E_MAX  131072
#define L5     5

// workspace: only Wp
#define WS_WP 0            // 512*3 : Wp = W_gcn[5] @ W_pos

// ---- K1: Wp rows, 256 blocks x 2 waves (one wave per row) ----
__global__ __launch_bounds__(256) void k1(
    const float* __restrict__ Wgcn, const float* __restrict__ Wpos,
    float* __restrict__ ws)
{
    int lane = threadIdx.x & 63;
    int w    = threadIdx.x >> 6;
    if (w >= 2) return;
    int row  = blockIdx.x * 2 + w;                 // 256*2 = 512 rows
    const float* Wr = Wgcn + (size_t)L5 * HID * HID + (size_t)row * HID;
    float a0 = 0.f, a1 = 0.f, a2 = 0.f;
    for (int j = lane; j < HID; j += 64) {         // coalesced row read
        float v = Wr[j];
        a0 += v * Wpos[j * 3 + 0];
        a1 += v * Wpos[j * 3 + 1];
        a2 += v * Wpos[j * 3 + 2];
    }
    for (int m = 32; m; m >>= 1) {
        a0 += __shfl_xor(a0, m);
        a1 += __shfl_xor(a1, m);
        a2 += __shfl_xor(a2, m);
    }
    if (lane == 0) {
        ws[WS_WP + row * 3 + 0] = a0;
        ws[WS_WP + row * 3 + 1] = a1;
        ws[WS_WP + row * 3 + 2] = a2;
    }
}

// ---- K2: everything else. 512 blocks, 2 ligand nodes per block ----
__global__ __launch_bounds__(256) void k2(
    const int*   __restrict__ ei,    const float* __restrict__ spos,
    const float* __restrict__ lpos,  const float* __restrict__ tarr,
    const float* __restrict__ Wt1,   const float* __restrict__ bt1,
    const float* __restrict__ Wt2,   const float* __restrict__ bt2,
    const float* __restrict__ Wlig,  const float* __restrict__ blig,
    const float* __restrict__ Wgate, const float* __restrict__ bgate,
    const float* __restrict__ Whb,
    const float* __restrict__ Wsurf, const float* __restrict__ bsurf,
    const float* __restrict__ bgcn,  const float* __restrict__ Wpos,
    const float* __restrict__ bpos,
    const float* __restrict__ ws,    float* __restrict__ out)
{
    __shared__ float s_emb[2][64];
    __shared__ float s_h1[2][256];
    __shared__ float s_red[2][2][64];      // [k-half][node][col]
    __shared__ float s_ht[2][64];
    __shared__ float s_agg[4][8];          // [wave][n*4 + {x,y,z,cnt}]
    __shared__ float s_foldp[4][15];       // per-wave fold partials
    __shared__ float s_fold[15];           // A3[9], bsp[3], bpout[3]
    __shared__ float s_out[4][2][3];       // [wave][node][3]
    int t    = threadIdx.x;
    int lane = t & 63;
    int w    = t >> 6;
    int b    = blockIdx.x;
    int i0   = b * 2;

    // ---- edge gather-scan: register partials for this block's 2 ligands ----
    float ag0x = 0.f, ag0y = 0.f, ag0z = 0.f, cn0 = 0.f;
    float ag1x = 0.f, ag1y = 0.f, ag1z = 0.f, cn1 = 0.f;
    {
        const int4* dst4 = (const int4*)(ei + E_MAX);
        #pragma unroll 4
        for (int it = 0; it < E_MAX / 1024; ++it) {     // 128 iters
            int idx = it * 256 + t;
            int4 dv = dst4[idx];
            int e0  = idx * 4;
            int dd[4] = {dv.x, dv.y, dv.z, dv.w};
            #pragma unroll
            for (int c = 0; c < 4; ++c) {
                unsigned li = (unsigned)(dd[c] - N_SURF - i0);
                if (li < 2u) {                           // real surface->lig edge
                    int s = ei[e0 + c];
                    float sx = spos[s * 3 + 0];
                    float sy = spos[s * 3 + 1];
                    float sz = spos[s * 3 + 2];
                    if (li == 0u) { ag0x += sx; ag0y += sy; ag0z += sz; cn0 += 1.f; }
                    else          { ag1x += sx; ag1y += sy; ag1z += sz; cn1 += 1.f; }
                }
            }
        }
        for (int m = 32; m; m >>= 1) {
            ag0x += __shfl_xor(ag0x, m); ag0y += __shfl_xor(ag0y, m);
            ag0z += __shfl_xor(ag0z, m); cn0  += __shfl_xor(cn0,  m);
            ag1x += __shfl_xor(ag1x, m); ag1y += __shfl_xor(ag1y, m);
            ag1z += __shfl_xor(ag1z, m); cn1  += __shfl_xor(cn1,  m);
        }
        if (lane == 0) {
            s_agg[w][0] = ag0x; s_agg[w][1] = ag0y; s_agg[w][2] = ag0z; s_agg[w][3] = cn0;
            s_agg[w][4] = ag1x; s_agg[w][5] = ag1y; s_agg[w][6] = ag1z; s_agg[w][7] = cn1;
        }
    }

    // ---- emb: waves 0,1 -> node w ----
    if (w < 2) {
        float tt = tarr[i0 + w];
        const float coef = -0.29710775f;   // -ln(10000)/31
        float ang = tt * expf(coef * (float)(lane & 31));
        s_emb[w][lane] = (lane < 32) ? sinf(ang) : cosf(ang);
    }
    __syncthreads();                       // A: s_emb, s_agg ready

    // ---- h1 = gelu(emb @ Wt1 + bt1): thread t owns column t, both nodes ----
    {
        float bb = bt1[t];
        float acc0 = bb, acc1 = bb;
        #pragma unroll 16
        for (int k = 0; k < 64; ++k) {
            float wv = Wt1[k * 256 + t];
            acc0 += s_emb[0][k] * wv;
            acc1 += s_emb[1][k] * wv;
        }
        s_h1[0][t] = 0.5f * acc0 * (1.f + erff(acc0 * 0.70710678f));
        s_h1[1][t] = 0.5f * acc1 * (1.f + erff(acc1 * 0.70710678f));
    }
    __syncthreads();                       // B: s_h1 ready

    // ---- ht partials: wave w -> node (w&1), k-half (w>>1)*128 ----
    {
        int n  = w & 1;
        int k0 = (w >> 1) * 128;
        float a0 = 0.f, a1 = 0.f, a2 = 0.f, a3 = 0.f;
        #pragma unroll 16
        for (int kk = 0; kk < 128; kk += 4) {
            int k = k0 + kk;
            a0 += s_h1[n][k + 0] * Wt2[(k + 0) * 64 + lane];
            a1 += s_h1[n][k + 1] * Wt2[(k + 1) * 64 + lane];
            a2 += s_h1[n][k + 2] * Wt2[(k + 2) * 64 + lane];
            a3 += s_h1[n][k + 3] * Wt2[(k + 3) * 64 + lane];
        }
        s_red[w >> 1][n][lane] = (a0 + a1) + (a2 + a3);
    }

    // ---- folds: 15 outputs, thread-parallel over k = {t, t+256} ----
    float wpa0, wpa1, wpa2, wpb0, wpb1, wpb2;
    {
        int ka = t, kb = t + 256;
        wpa0 = ws[WS_WP + ka * 3 + 0]; wpa1 = ws[WS_WP + ka * 3 + 1]; wpa2 = ws[WS_WP + ka * 3 + 2];
        wpb0 = ws[WS_WP + kb * 3 + 0]; wpb1 = ws[WS_WP + kb * 3 + 1]; wpb2 = ws[WS_WP + kb * 3 + 2];
        float f[15];
        #pragma unroll
        for (int a = 0; a < 3; ++a) {
            float ra = Wsurf[a * HID + ka], rb = Wsurf[a * HID + kb];
            f[a * 3 + 0] = ra * wpa0 + rb * wpb0;
            f[a * 3 + 1] = ra * wpa1 + rb * wpb1;
            f[a * 3 + 2] = ra * wpa2 + rb * wpb2;
        }
        {
            float ra = bsurf[ka], rb = bsurf[kb];
            f[9]  = ra * wpa0 + rb * wpb0;
            f[10] = ra * wpa1 + rb * wpb1;
            f[11] = ra * wpa2 + rb * wpb2;
        }
        {
            float ra = bgcn[L5 * HID + ka], rb = bgcn[L5 * HID + kb];
            f[12] = ra * Wpos[ka * 3 + 0] + rb * Wpos[kb * 3 + 0];
            f[13] = ra * Wpos[ka * 3 + 1] + rb * Wpos[kb * 3 + 1];
            f[14] = ra * Wpos[ka * 3 + 2] + rb * Wpos[kb * 3 + 2];
        }
        #pragma unroll
        for (int o = 0; o < 15; ++o)
            for (int m = 32; m; m >>= 1) f[o] += __shfl_xor(f[o], m);
        if (lane == 0) {
            #pragma unroll
            for (int o = 0; o < 15; ++o) s_foldp[w][o] = f[o];
        }
    }
    __syncthreads();                       // C: s_red, s_foldp ready
    if (t < 128) {
        int n = t >> 6;
        s_ht[n][lane] = bt2[lane] + s_red[0][n][lane] + s_red[1][n][lane];
    } else if (t < 143) {
        int o = t - 128;
        float v = s_foldp[0][o] + s_foldp[1][o] + s_foldp[2][o] + s_foldp[3][o];
        s_fold[o] = v + ((o >= 12) ? bpos[o - 12] : 0.f);
    }
    __syncthreads();                       // D: s_ht, s_fold ready

    // ---- gate + inline hbias + Wp-fold: cols t, t+256, both nodes ----
    float px[2], py[2], pz[2];
    #pragma unroll
    for (int n = 0; n < 2; ++n) {
        px[n] = lpos[(i0 + n) * 3 + 0];
        py[n] = lpos[(i0 + n) * 3 + 1];
        pz[n] = lpos[(i0 + n) * 3 + 2];
    }
    float a[2][3] = {};
    #pragma unroll
    for (int r = 0; r < 2; ++r) {
        int j = r * 256 + t;
        float bg = bgate[j];
        float g0 = bg, g1 = bg, hb0 = 0.f, hb1 = 0.f;
        #pragma unroll 16
        for (int k = 0; k < 64; ++k) {
            float wg = Wgate[k * 512 + j];
            float wh = Whb[k * 512 + j];
            float h0 = s_ht[0][k], h1v = s_ht[1][k];
            g0  += h0  * wg;  g1  += h1v * wg;
            hb0 += h0  * wh;  hb1 += h1v * wh;
        }
        float wl0 = Wlig[j], wl1 = Wlig[512 + j], wl2 = Wlig[1024 + j], bl = blig[j];
        float wp0 = (r == 0) ? wpa0 : wpb0;
        float wp1 = (r == 0) ? wpa1 : wpb1;
        float wp2 = (r == 0) ? wpa2 : wpb2;
        float g[2]  = {g0, g1};
        float hb[2] = {hb0, hb1};
        #pragma unroll
        for (int n = 0; n < 2; ++n) {
            float p  = bl + px[n] * wl0 + py[n] * wl1 + pz[n] * wl2;
            float hl = p * (1.f / (1.f + expf(-g[n]))) + hb[n];   // h_lig[j]
            a[n][0] += hl * wp0;
            a[n][1] += hl * wp1;
            a[n][2] += hl * wp2;
        }
    }
    #pragma unroll
    for (int n = 0; n < 2; ++n)
        #pragma unroll
        for (int jp = 0; jp < 3; ++jp)
            for (int m = 32; m; m >>= 1) a[n][jp] += __shfl_xor(a[n][jp], m);
    if (lane == 0)
        #pragma unroll
        for (int n = 0; n < 2; ++n)
            #pragma unroll
            for (int jp = 0; jp < 3; ++jp) s_out[w][n][jp] = a[n][jp];
    __syncthreads();                       // E: s_out ready

    if (t < 2) {                           // thread t -> node i0+t epilogue
        int n = t, i = i0 + n;
        float d    = s_agg[0][n * 4 + 3] + s_agg[1][n * 4 + 3] + s_agg[2][n * 4 + 3] + s_agg[3][n * 4 + 3];
        float aggx = s_agg[0][n * 4 + 0] + s_agg[1][n * 4 + 0] + s_agg[2][n * 4 + 0] + s_agg[3][n * 4 + 0];
        float aggy = s_agg[0][n * 4 + 1] + s_agg[1][n * 4 + 1] + s_agg[2][n * 4 + 1] + s_agg[3][n * 4 + 1];
        float aggz = s_agg[0][n * 4 + 2] + s_agg[1][n * 4 + 2] + s_agg[2][n * 4 + 2] + s_agg[3][n * 4 + 2];
        float s1 = 1.f / sqrtf(1.f + d);
        float s2 = 1.f / (1.f + d);
        float c  = s1 * d;
        float ax = s1 * aggx, ay = s1 * aggy, az = s1 * aggz;
        #pragma unroll
        for (int jp = 0; jp < 3; ++jp) {
            float bb = s_out[0][n][jp] + s_out[1][n][jp] + s_out[2][n][jp] + s_out[3][n][jp];
            out[i * 3 + jp] = ax * s_fold[0 + jp] +
                              ay * s_fold[3 + jp] +
                              az * s_fold[6 + jp] +
                              c  * s_fold[9 + jp] +
                              s2 * bb             +
                              s_fold[12 + jp];
        }
    }
}

extern "C" void kernel_launch(void* const* d_in, const int* in_sizes, int n_in,
                              void* d_out, int out_size, void* d_ws, size_t ws_size,
                              hipStream_t stream) {
    const float* spos  = (const float*)d_in[0];
    const float* lpos  = (const float*)d_in[1];
    const float* tarr  = (const float*)d_in[2];
    const int*   ei    = (const int*)  d_in[3];
    const float* Wsurf = (const float*)d_in[6];
    const float* bsurf = (const float*)d_in[7];
    const float* Wt1   = (const float*)d_in[8];
    const float* bt1   = (const float*)d_in[9];
    const float* Wt2   = (const float*)d_in[10];
    const float* bt2   = (const float*)d_in[11];
    const float* Wlig  = (const float*)d_in[12];
    const float* blig  = (const float*)d_in[13];
    const float* Wgate = (const float*)d_in[14];
    const float* bgate = (const float*)d_in[15];
    const float* Whb   = (const float*)d_in[16];
    const float* Wgcn  = (const float*)d_in[17];
    const float* bgcn  = (const float*)d_in[18];
    const float* Wpos  = (const float*)d_in[19];
    const float* bpos  = (const float*)d_in[20];
    float* ws  = (float*)d_ws;
    float* out = (float*)d_out;

    hipLaunchKernelGGL(k1, dim3(256), dim3(256), 0, stream, Wgcn, Wpos, ws);
    hipLaunchKernelGGL(k2, dim3(N_LIG / 2), dim3(256), 0, stream,
                       ei, spos, lpos, tarr, Wt1, bt1, Wt2, bt2,
                       Wlig, blig, Wgate, bgate, Whb,
                       Wsurf, bsurf, bgcn, Wpos, bpos, ws, out);
}

// Round 12
// 36.483 us; speedup vs baseline: 1.5580x; 1.5580x over previous
//
#include <hip/hip_runtime.h>
#include <math.h>

#define N_SURF 40000
#define N_LIG  1024
#define HID    512
#define E_MAX  131072
#define L5     5

// workspace float layout
#define WS_WP     0        // 512*3  : Wp = W_gcn[5] @ W_pos
#define WS_A3     1536     // 9      : W_surf @ Wp
#define WS_BSP    1545     // 3      : b_surf @ Wp
#define WS_BPOUT  1548     // 3      : b_gcn[5]@W_pos + b_pos
#define WS_WHBP   1552     // 64*3   : W_hbias @ Wp
#define WS_AGG    1744     // 1024*3 : sum of surface_pos over in-edges
#define WS_CNT    4816     // 1024   : in-degree
#define WS_ZERO_BEGIN 1744
#define WS_ZERO_COUNT 4096

// ---- prep1: Wp = W_gcn[5]@W_pos (one wave per row) + zero AGG/CNT ----
__global__ __launch_bounds__(256) void k_prep1(
    const float* __restrict__ Wgcn, const float* __restrict__ Wpos,
    float* __restrict__ ws)
{
    int lane = threadIdx.x & 63;
    int w    = threadIdx.x >> 6;
    int k    = blockIdx.x * 4 + w;                 // 128 blocks * 4 waves = 512 rows
    const float* Wg5 = Wgcn + (size_t)L5 * HID * HID + (size_t)k * HID;
    float a0 = 0.f, a1 = 0.f, a2 = 0.f;
    for (int j = lane; j < HID; j += 64) {         // coalesced row read
        float v = Wg5[j];
        a0 += v * Wpos[j * 3 + 0];
        a1 += v * Wpos[j * 3 + 1];
        a2 += v * Wpos[j * 3 + 2];
    }
    for (int m = 32; m; m >>= 1) {
        a0 += __shfl_xor(a0, m);
        a1 += __shfl_xor(a1, m);
        a2 += __shfl_xor(a2, m);
    }
    if (lane == 0) {
        ws[WS_WP + k * 3 + 0] = a0;
        ws[WS_WP + k * 3 + 1] = a1;
        ws[WS_WP + k * 3 + 2] = a2;
    }
    int idx = blockIdx.x * blockDim.x + threadIdx.x;   // 32768 threads cover 4096
    if (idx < WS_ZERO_COUNT) ws[WS_ZERO_BEGIN + idx] = 0.f;
}

// ---- k_mid: blocks 0..51 = Wp-dependent folds (207 outputs, one wave each);
//             blocks 52..563 = edge scatter (256 edges each) ----
__global__ __launch_bounds__(256) void k_mid(
    const float* __restrict__ Wsurf, const float* __restrict__ bsurf,
    const float* __restrict__ bgcn,  const float* __restrict__ Wpos,
    const float* __restrict__ bpos,  const float* __restrict__ Whb,
    const int*   __restrict__ ei,    const float* __restrict__ spos,
    float* __restrict__ ws)
{
    if (blockIdx.x < 52) {
        int lane = threadIdx.x & 63;
        int w    = threadIdx.x >> 6;
        int o    = blockIdx.x * 4 + w;             // 52*4 >= 207 outputs
        if (o >= 207) return;
        float acc = 0.f;
        if (o < 9) {
            int a = o / 3, jp = o - a * 3;
            for (int k = lane; k < HID; k += 64)
                acc += Wsurf[a * HID + k] * ws[WS_WP + k * 3 + jp];
        } else if (o < 12) {
            int jp = o - 9;
            for (int k = lane; k < HID; k += 64)
                acc += bsurf[k] * ws[WS_WP + k * 3 + jp];
        } else if (o < 15) {
            int jp = o - 12;
            for (int j = lane; j < HID; j += 64)
                acc += bgcn[L5 * HID + j] * Wpos[j * 3 + jp];
        } else {
            int r = (o - 15) / 3, jp = (o - 15) % 3;
            for (int j = lane; j < HID; j += 64)
                acc += Whb[r * HID + j] * ws[WS_WP + j * 3 + jp];
        }
        for (int m = 32; m; m >>= 1) acc += __shfl_xor(acc, m);
        if (lane == 0) {
            if (o < 9)        ws[WS_A3 + o] = acc;
            else if (o < 12)  ws[WS_BSP + (o - 9)] = acc;
            else if (o < 15)  ws[WS_BPOUT + (o - 12)] = acc + bpos[o - 12];
            else              ws[WS_WHBP + (o - 15)] = acc;
        }
    } else {
        int e = (blockIdx.x - 52) * 256 + threadIdx.x;   // 512 blocks * 256 = E_MAX
        int s = ei[e];
        int d = ei[E_MAX + e];
        if (s < N_SURF && d >= N_SURF) {   // surface -> ligand edges only
            int li = d - N_SURF;
            atomicAdd(&ws[WS_AGG + li * 3 + 0], spos[s * 3 + 0]);
            atomicAdd(&ws[WS_AGG + li * 3 + 1], spos[s * 3 + 1]);
            atomicAdd(&ws[WS_AGG + li * 3 + 2], spos[s * 3 + 2]);
            atomicAdd(&ws[WS_CNT + li], 1.0f);
        }
    }
}

// ---- k2: per-ligand pipeline, 2 nodes per block (512 blocks, 2 blk/CU) ----
__global__ __launch_bounds__(256) void k2(
    const float* __restrict__ lpos,  const float* __restrict__ tarr,
    const float* __restrict__ Wt1,   const float* __restrict__ bt1,
    const float* __restrict__ Wt2,   const float* __restrict__ bt2,
    const float* __restrict__ Wlig,  const float* __restrict__ blig,
    const float* __restrict__ Wgate, const float* __restrict__ bgate,
    const float* __restrict__ ws,    float* __restrict__ out)
{
    __shared__ float s_emb[2][64];
    __shared__ float s_h1[2][256];
    __shared__ float s_red[2][2][64];      // [k-half][node][col]
    __shared__ float s_ht[2][64];
    __shared__ float s_out[4][2][3];       // [wave][node][3]
    int t    = threadIdx.x;
    int lane = t & 63;
    int w    = t >> 6;
    int b    = blockIdx.x;
    int i0   = b * 2;

    // emb: waves 0,1 -> node w
    if (w < 2) {
        float tt = tarr[i0 + w];
        const float coef = -0.29710775f;   // -ln(10000)/31
        float ang = tt * expf(coef * (float)(lane & 31));
        s_emb[w][lane] = (lane < 32) ? sinf(ang) : cosf(ang);
    }
    __syncthreads();
    // h1 = gelu(emb @ Wt1 + bt1): thread t owns column t for both nodes
    {
        float bb = bt1[t];
        float acc0 = bb, acc1 = bb;
        #pragma unroll 16
        for (int k = 0; k < 64; ++k) {
            float wv = Wt1[k * 256 + t];
            acc0 += s_emb[0][k] * wv;
            acc1 += s_emb[1][k] * wv;
        }
        s_h1[0][t] = 0.5f * acc0 * (1.f + erff(acc0 * 0.70710678f));
        s_h1[1][t] = 0.5f * acc1 * (1.f + erff(acc1 * 0.70710678f));
    }
    __syncthreads();
    // ht partials: wave w -> node (w&1), k-half (w>>1)*128
    {
        int n  = w & 1;
        int k0 = (w >> 1) * 128;
        float a0 = 0.f, a1 = 0.f, a2 = 0.f, a3 = 0.f;
        #pragma unroll 16
        for (int kk = 0; kk < 128; kk += 4) {
            int k = k0 + kk;
            a0 += s_h1[n][k + 0] * Wt2[(k + 0) * 64 + lane];
            a1 += s_h1[n][k + 1] * Wt2[(k + 1) * 64 + lane];
            a2 += s_h1[n][k + 2] * Wt2[(k + 2) * 64 + lane];
            a3 += s_h1[n][k + 3] * Wt2[(k + 3) * 64 + lane];
        }
        s_red[w >> 1][n][lane] = (a0 + a1) + (a2 + a3);
    }
    __syncthreads();
    if (t < 128) {
        int n = t >> 6;
        s_ht[n][lane] = bt2[lane] + s_red[0][n][lane] + s_red[1][n][lane];
    }
    __syncthreads();

    float px[2], py[2], pz[2];
    #pragma unroll
    for (int n = 0; n < 2; ++n) {
        px[n] = lpos[(i0 + n) * 3 + 0];
        py[n] = lpos[(i0 + n) * 3 + 1];
        pz[n] = lpos[(i0 + n) * 3 + 2];
    }
    float a[2][3] = {};
    // gate + Wp-fold: thread t owns cols t, t+256 (hbias folded via Whbp)
    #pragma unroll
    for (int r = 0; r < 2; ++r) {
        int j = r * 256 + t;
        float bg = bgate[j];
        float g0 = bg, g1 = bg;
        #pragma unroll 16
        for (int k = 0; k < 64; ++k) {
            float wg = Wgate[k * 512 + j];
            g0 += s_ht[0][k] * wg;
            g1 += s_ht[1][k] * wg;
        }
        float wl0 = Wlig[j], wl1 = Wlig[512 + j], wl2 = Wlig[1024 + j], bl = blig[j];
        float wp0 = ws[WS_WP + j * 3 + 0];
        float wp1 = ws[WS_WP + j * 3 + 1];
        float wp2 = ws[WS_WP + j * 3 + 2];
        float g[2] = {g0, g1};
        #pragma unroll
        for (int n = 0; n < 2; ++n) {
            float p  = bl + px[n] * wl0 + py[n] * wl1 + pz[n] * wl2;
            float hl = p * (1.f / (1.f + expf(-g[n])));
            a[n][0] += hl * wp0;
            a[n][1] += hl * wp1;
            a[n][2] += hl * wp2;
        }
    }
    // + h_time @ Whbp (64x3 precomputed)
    if (t < 64) {
        float h0  = ws[WS_WHBP + t * 3 + 0];
        float h1v = ws[WS_WHBP + t * 3 + 1];
        float h2  = ws[WS_WHBP + t * 3 + 2];
        #pragma unroll
        for (int n = 0; n < 2; ++n) {
            float ht = s_ht[n][t];
            a[n][0] += ht * h0;
            a[n][1] += ht * h1v;
            a[n][2] += ht * h2;
        }
    }
    #pragma unroll
    for (int n = 0; n < 2; ++n)
        #pragma unroll
        for (int jp = 0; jp < 3; ++jp)
            for (int m = 32; m; m >>= 1) a[n][jp] += __shfl_xor(a[n][jp], m);
    if (lane == 0)
        #pragma unroll
        for (int n = 0; n < 2; ++n)
            #pragma unroll
            for (int jp = 0; jp < 3; ++jp) s_out[w][n][jp] = a[n][jp];
    __syncthreads();
    if (t < 2) {   // thread t -> node i0+t epilogue
        int n = t, i = i0 + n;
        float d  = ws[WS_CNT + i];
        float s1 = 1.f / sqrtf(1.f + d);
        float s2 = 1.f / (1.f + d);
        float c  = s1 * d;
        float ax = s1 * ws[WS_AGG + i * 3 + 0];
        float ay = s1 * ws[WS_AGG + i * 3 + 1];
        float az = s1 * ws[WS_AGG + i * 3 + 2];
        #pragma unroll
        for (int jp = 0; jp < 3; ++jp) {
            float bb = s_out[0][n][jp] + s_out[1][n][jp] + s_out[2][n][jp] + s_out[3][n][jp];
            out[i * 3 + jp] = ax * ws[WS_A3 + 0 + jp] +
                              ay * ws[WS_A3 + 3 + jp] +
                              az * ws[WS_A3 + 6 + jp] +
                              c  * ws[WS_BSP + jp]    +
                              s2 * bb                 +
                              ws[WS_BPOUT + jp];
        }
    }
}

extern "C" void kernel_launch(void* const* d_in, const int* in_sizes, int n_in,
                              void* d_out, int out_size, void* d_ws, size_t ws_size,
                              hipStream_t stream) {
    const float* spos  = (const float*)d_in[0];
    const float* lpos  = (const float*)d_in[1];
    const float* tarr  = (const float*)d_in[2];
    const int*   ei    = (const int*)  d_in[3];
    const float* Wsurf = (const float*)d_in[6];
    const float* bsurf = (const float*)d_in[7];
    const float* Wt1   = (const float*)d_in[8];
    const float* bt1   = (const float*)d_in[9];
    const float* Wt2   = (const float*)d_in[10];
    const float* bt2   = (const float*)d_in[11];
    const float* Wlig  = (const float*)d_in[12];
    const float* blig  = (const float*)d_in[13];
    const float* Wgate = (const float*)d_in[14];
    const float* bgate = (const float*)d_in[15];
    const float* Whb   = (const float*)d_in[16];
    const float* Wgcn  = (const float*)d_in[17];
    const float* bgcn  = (const float*)d_in[18];
    const float* Wpos  = (const float*)d_in[19];
    const float* bpos  = (const float*)d_in[20];
    float* ws  = (float*)d_ws;
    float* out = (float*)d_out;

    hipLaunchKernelGGL(k_prep1, dim3(128), dim3(256), 0, stream, Wgcn, Wpos, ws);
    hipLaunchKernelGGL(k_mid,   dim3(52 + E_MAX / 256), dim3(256), 0, stream,
                       Wsurf, bsurf, bgcn, Wpos, bpos, Whb, ei, spos, ws);
    hipLaunchKernelGGL(k2,      dim3(N_LIG / 2), dim3(256), 0, stream,
                       lpos, tarr, Wt1, bt1, Wt2, bt2,
                       Wlig, blig, Wgate, bgate, ws, out);
}